// Round 5
// baseline (79.199 us; speedup 1.0000x reference)
//
#include <hip/hip_runtime.h>
#include <cstdint>
#include <cstddef>

#define N_NODES 50000
#define M_MOLS  512
#define DIMK    256
#define ODIM    256

// sampled-boundary parameters
#define NCH   99
#define CW    32
#define NSAMP (NCH * CW)      // 3168 sampled columns, monotone molid

#define NB_SAMP  NCH
#define NB_WPACK 32
#define NB_ALIGN 1563         // 50000 rows * 8 threads / 256
#define K1_GRID  (NB_SAMP + NB_WPACK + NB_ALIGN)

// K3: interleaved writer + pool
#define POOL_BLOCKS 512
#define WCOLS 25              // column chunks of 2048 (512 thr * float4)
#define WROWS 8               // m-rows per writer block
#define NB_WRITE (WCOLS * (M_MOLS / WROWS))  // 1600
#define K3_GRID (POOL_BLOCKS + NB_WRITE)     // 2112
#define NF4   (N_NODES / 4)   // 12500 float4 per out1 row

typedef float  f32x4  __attribute__((ext_vector_type(4)));
typedef __bf16 bf16x8 __attribute__((ext_vector_type(8)));

static __device__ __forceinline__ short f2bf(float f) {
  unsigned u = __builtin_bit_cast(unsigned, f);
  u = u + 0x7fffu + ((u >> 16) & 1u);   // RNE to bf16
  return (short)(u >> 16);
}

static __device__ __forceinline__ int chunk_base(int c) {
  return (c < NCH - 1) ? c * 512 : (N_NODES - CW);   // 49968 for last
}
static __device__ __forceinline__ int scol(int idx) {
  return chunk_base(idx >> 5) + (idx & 31);
}

// ---------------- K1: sampled molid + W pack + align GEMV ----------------
__global__ __launch_bounds__(256) void k_prep(
    const float* __restrict__ x, const float* __restrict__ mat,
    const float* __restrict__ W, const float* __restrict__ wa,
    const float* __restrict__ ba,
    float* __restrict__ a, int* __restrict__ smolid, int4* __restrict__ wp) {
  int b = blockIdx.x, t = threadIdx.x;
  if (b < NB_SAMP) {
    int base = chunk_base(b);
    int cp = (t & 15) * 2;      // column pair
    int rg = t >> 4;            // 16 row-groups of 32 rows
    int idx = -1, idy = -1;
    const float* p0 = mat + (size_t)(rg * 32) * N_NODES + base + cp;
#pragma unroll 16
    for (int r = 0; r < 32; r++) {
      float2 v = *(const float2*)(p0 + (size_t)r * N_NODES);
      if (v.x != 0.f) idx = rg * 32 + r;
      if (v.y != 0.f) idy = rg * 32 + r;
    }
    __shared__ int sm[16][32];
    sm[rg][cp] = idx; sm[rg][cp + 1] = idy;
    __syncthreads();
    if (t < 32) {
      int best = -1;
#pragma unroll
      for (int g = 0; g < 16; g++) best = max(best, sm[g][t]);
      smolid[b * CW + t] = best;
    }
  } else if (b < NB_SAMP + NB_WPACK) {
    // W pack into MFMA B-fragment layout (bf16)
    int g  = (b - NB_SAMP) * 256 + t;   // 0..8191
    int l  = g & 63;
    int Ju = g >> 6;
    int J  = Ju >> 3, u = Ju & 7;
    int j  = J * 16 + (l & 15);
    int k0 = u * 32 + (l >> 4) * 8;
    short sv[8];
#pragma unroll
    for (int i = 0; i < 8; i++) sv[i] = f2bf(W[(size_t)(k0 + i) * ODIM + j]);
    wp[Ju * 64 + l] = *(int4*)sv;
  } else {
    // align: a[n] = x[n,:].w_align + b_align, 8 threads per row
    int tid = (b - NB_SAMP - NB_WPACK) * 256 + t;
    int row = tid >> 3, sub = tid & 7;
    if (row >= N_NODES) return;
    const float4* xr = (const float4*)(x + (size_t)row * DIMK) + sub * 8;
    const float4* wr = (const float4*)wa + sub * 8;
    float s = 0.f;
#pragma unroll
    for (int i = 0; i < 8; i++) {
      float4 xv = xr[i], wv = wr[i];
      s += xv.x * wv.x + xv.y * wv.y + xv.z * wv.z + xv.w * wv.w;
    }
    s += __shfl_xor(s, 1); s += __shfl_xor(s, 2); s += __shfl_xor(s, 4);
    if (sub == 0) a[row] = s + ba[0];
  }
}

// ---------------- K2: bounds + softmax stats -> strt[], wval[] ----------------
__global__ __launch_bounds__(256) void k_bstats(
    const float* __restrict__ a, const float* __restrict__ mat,
    const int* __restrict__ smolid, int* __restrict__ strt,
    float* __restrict__ wval) {
  int m = blockIdx.x, t = threadIdx.x;
  __shared__ float fred[4];
  __shared__ int   ired[4];
  __shared__ int   sseg[2];

  for (int which = 0; which < 2; which++) {
    int mm = m + which;
    int lo = 0, hi = NSAMP;
    while (lo < hi) { int mid = (lo + hi) >> 1; if (smolid[mid] < mm) lo = mid + 1; else hi = mid; }
    int res;
    if (lo == 0) res = 0;
    else if (lo >= NSAMP) res = N_NODES;
    else {
      int chi = scol(lo), clo = scol(lo - 1);
      if (chi == clo + 1) res = chi;
      else {
        int bh = smolid[lo];
        int Wd = chi - clo;              // columns clo+1 .. chi
        res = -1;
        for (int r = mm; r <= bh; r++) {
          const float* rp = mat + (size_t)r * N_NODES;
          int f = 0x7fffffff;
          for (int i = t; i < Wd; i += 256) {
            int col = clo + 1 + i;
            if (rp[col] != 0.f) { f = col; break; }  // ascending per thread
          }
#pragma unroll
          for (int o = 1; o < 64; o <<= 1) f = min(f, __shfl_xor(f, o));
          if ((t & 63) == 0) ired[t >> 6] = f;
          __syncthreads();
          int gmin = min(min(ired[0], ired[1]), min(ired[2], ired[3]));
          __syncthreads();
          if (gmin != 0x7fffffff) { res = gmin; break; }
        }
        if (res < 0) res = chi;   // unreachable safety
      }
    }
    if (t == 0) sseg[which] = res;
  }
  __syncthreads();
  int s = sseg[0], e = sseg[1];
  if (t == 0) {
    strt[m] = s;
    if (m == M_MOLS - 1) strt[M_MOLS] = e;
  }

  float mx = -3e38f;
  for (int i = s + t; i < e; i += 256) mx = fmaxf(mx, a[i]);
#pragma unroll
  for (int o = 1; o < 64; o <<= 1) mx = fmaxf(mx, __shfl_xor(mx, o));
  if ((t & 63) == 0) fred[t >> 6] = mx;
  __syncthreads();
  mx = fmaxf(fmaxf(fred[0], fred[1]), fmaxf(fred[2], fred[3]));
  __syncthreads();
  float sm = 0.f;
  for (int i = s + t; i < e; i += 256) sm += __expf(a[i] - mx);
#pragma unroll
  for (int o = 1; o < 64; o <<= 1) sm += __shfl_xor(sm, o);
  if ((t & 63) == 0) fred[t >> 6] = sm;
  __syncthreads();
  sm = fred[0] + fred[1] + fred[2] + fred[3];
  float inv = (sm > 0.f) ? 1.f / sm : 0.f;
  for (int i = s + t; i < e; i += 256) wval[i] = __expf(a[i] - mx) * inv;
}

// ---------------- K3: full-row weights writer + fused MFMA pool ----------------
__global__ __launch_bounds__(512, 4) void k_out(
    const float* __restrict__ x, const float* __restrict__ wval,
    const int* __restrict__ strt, const int4* __restrict__ wp,
    const float* __restrict__ bias, float* __restrict__ out0,
    float* __restrict__ out1) {
  int b  = blockIdx.x;
  int pb = b >> 2;
  bool isPool = ((b & 3) == 0) && (pb < POOL_BLOCKS);
  int t = threadIdx.x;

  if (!isPool) {
    // ---- writer: 2048 columns x 8 m-rows of out1 (zeros + weight window)
    int before = (pb < POOL_BLOCKS) ? (pb + 1) : POOL_BLOCKS;
    int wb = b - before;                 // 0..1599
    int mc = wb / WCOLS;                 // 0..63
    int c  = wb % WCOLS;                 // 0..24
    int n4 = c * 512 + t;
    if (n4 >= NF4) return;
    int n = n4 * 4;
    float4 w = *(const float4*)(wval + n);
    int m0 = mc * WROWS;
#pragma unroll
    for (int r = 0; r < WROWS; r++) {
      int m = m0 + r;
      int s = strt[m], e = strt[m + 1];
      float4 o;
      o.x = ((unsigned)(n     - s) < (unsigned)(e - s)) ? w.x : 0.f;
      o.y = ((unsigned)(n + 1 - s) < (unsigned)(e - s)) ? w.y : 0.f;
      o.z = ((unsigned)(n + 2 - s) < (unsigned)(e - s)) ? w.z : 0.f;
      o.w = ((unsigned)(n + 3 - s) < (unsigned)(e - s)) ? w.w : 0.f;
      *(float4*)(out1 + (size_t)m * N_NODES + n) = o;
    }
    return;
  }

  // ---- fused h-GEMM + pool for molecule m = pb (x is L3-hot after K1)
  int m = pb;
  int seg_s = strt[m], seg_e = strt[m + 1];
  int L = seg_e - seg_s;
  int wv_id = t >> 6, l = t & 63;

  bf16x8 wfrag[2][8];
#pragma unroll
  for (int t2 = 0; t2 < 2; t2++)
#pragma unroll
    for (int u = 0; u < 8; u++)
      wfrag[t2][u] = __builtin_bit_cast(bf16x8, wp[((wv_id * 2 + t2) * 8 + u) * 64 + l]);
  float bias_r[2];
#pragma unroll
  for (int t2 = 0; t2 < 2; t2++) bias_r[t2] = bias[wv_id * 32 + t2 * 16 + (l & 15)];

  float pooled[2] = {0.f, 0.f};
  int r = l & 15, g = l >> 4;
  int swr = (r & 7) << 4;

  __shared__ __align__(16) short xs[16 * 256];
  __shared__ float wt[16];

  int srow = t >> 5;            // staging: 16 rows, 32 threads each
  int c0b  = (t & 31) * 16;     // byte col offset within row
  int ssw  = (srow & 7) << 4;
  char* lb = (char*)xs;

  int nt2 = (L + 15) >> 4;
  for (int tile = 0; tile < nt2; tile++) {
    int base = seg_s + tile * 16;
    __syncthreads();
    {
      int n = base + srow;
      short sv[8];
      if (n < seg_e) {
        const float4* src = (const float4*)(x + (size_t)n * DIMK) + (t & 31) * 2;
        float4 A = src[0], B = src[1];
        sv[0] = f2bf(A.x); sv[1] = f2bf(A.y); sv[2] = f2bf(A.z); sv[3] = f2bf(A.w);
        sv[4] = f2bf(B.x); sv[5] = f2bf(B.y); sv[6] = f2bf(B.z); sv[7] = f2bf(B.w);
      } else {
#pragma unroll
        for (int i = 0; i < 8; i++) sv[i] = 0;
      }
      *(int4*)(lb + (srow << 9) + (c0b ^ ssw)) = *(int4*)sv;
      if (t < 16) {
        int nn = base + t;
        wt[t] = (nn < seg_e) ? wval[nn] : 0.f;
      }
    }
    __syncthreads();
    bf16x8 af[8];
#pragma unroll
    for (int u = 0; u < 8; u++)
      af[u] = __builtin_bit_cast(bf16x8,
                *(const int4*)(lb + (r << 9) + (((u << 6) + (g << 4)) ^ swr)));
#pragma unroll
    for (int t2 = 0; t2 < 2; t2++) {
      f32x4 acc = {0.f, 0.f, 0.f, 0.f};
#pragma unroll
      for (int u = 0; u < 8; u++)
        acc = __builtin_amdgcn_mfma_f32_16x16x32_bf16(af[u], wfrag[t2][u], acc, 0, 0, 0);
      float p = 0.f;
#pragma unroll
      for (int i = 0; i < 4; i++) {
        float h = acc[i] + bias_r[t2];
        h = h > 0.f ? h : 0.01f * h;
        p += wt[(g << 2) + i] * h;
      }
      pooled[t2] += p;
    }
  }
#pragma unroll
  for (int t2 = 0; t2 < 2; t2++) {
    float p = pooled[t2];
    p += __shfl_xor(p, 16);
    p += __shfl_xor(p, 32);
    pooled[t2] = p;
  }
  if (l < 16) {
#pragma unroll
    for (int t2 = 0; t2 < 2; t2++)
      out0[m * ODIM + wv_id * 32 + t2 * 16 + l] = pooled[t2];
  }
}

extern "C" void kernel_launch(void* const* d_in, const int* in_sizes, int n_in,
                              void* d_out, int out_size, void* d_ws, size_t ws_size,
                              hipStream_t stream) {
  const float* x   = (const float*)d_in[0];
  const float* mat = (const float*)d_in[1];
  // d_in[2] (mol_node_mask) redundant with mol_node_matrix — never read
  const float* W   = (const float*)d_in[3];
  const float* bA  = (const float*)d_in[4];
  const float* wa  = (const float*)d_in[5];
  const float* ba  = (const float*)d_in[6];

  float* out0 = (float*)d_out;
  float* out1 = out0 + (size_t)M_MOLS * ODIM;

  char*  ws     = (char*)d_ws;
  float* a      = (float*)(ws);              // 50000 f
  int*   smolid = (int*)  (ws + 200064);     // 3168 i
  int*   strt   = (int*)  (ws + 212800);     // 513 i
  float* wval   = (float*)(ws + 214912);     // 50000 f
  int4*  wp     = (int4*) (ws + 414912);     // 128 KiB

  k_prep  <<<K1_GRID, 256, 0, stream>>>(x, mat, W, wa, ba, a, smolid, wp);
  k_bstats<<<M_MOLS, 256, 0, stream>>>(a, mat, smolid, strt, wval);
  k_out   <<<K3_GRID, 512, 0, stream>>>(x, wval, strt, wp, bA, out0, out1);
}

// Round 6
// 56.793 us; speedup vs baseline: 1.3945x; 1.3945x over previous
//
#include <hip/hip_runtime.h>
#include <cstdint>
#include <cstddef>

#define N_NODES 50000
#define M_MOLS  512
#define DIMK    256
#define ODIM    256

// sampled-boundary parameters
#define NCH   99
#define CW    32
#define NSAMP (NCH * CW)      // 3168 sampled columns, monotone molid
#define NGAP  (NCH - 1)       // 98 inter-chunk gaps

#define NB_WPACK 32
#define B2_GRID  (NGAP + NCH + 1 + NB_WPACK)   // 230

#define NF4   (N_NODES / 4)   // 12500 float4 per out1 row
#define HALF4 6250            // float4s per writer block
#define A_CAP 1024            // max segment length in LDS (mean ~98, max ~140)

typedef float  f32x4  __attribute__((ext_vector_type(4)));
typedef __bf16 bf16x8 __attribute__((ext_vector_type(8)));

static __device__ __forceinline__ short f2bf(float f) {
  unsigned u = __builtin_bit_cast(unsigned, f);
  u = u + 0x7fffu + ((u >> 16) & 1u);   // RNE to bf16
  return (short)(u >> 16);
}

static __device__ __forceinline__ int chunk_base(int c) {
  return (c < NCH - 1) ? c * 512 : (N_NODES - CW);   // 49968 for last
}

// ---------------- K0a: sampled molid (99 blocks) ----------------
__global__ __launch_bounds__(256) void k_samp(
    const float* __restrict__ mat, int* __restrict__ smolid) {
  int b = blockIdx.x, t = threadIdx.x;
  int base = chunk_base(b);
  int cp = (t & 15) * 2;      // column pair
  int rg = t >> 4;            // 16 row-groups of 32 rows
  int idx = -1, idy = -1;
  const float* p0 = mat + (size_t)(rg * 32) * N_NODES + base + cp;
#pragma unroll 16
  for (int r = 0; r < 32; r++) {
    float2 v = *(const float2*)(p0 + (size_t)r * N_NODES);
    if (v.x != 0.f) idx = rg * 32 + r;
    if (v.y != 0.f) idy = rg * 32 + r;
  }
  __shared__ int sm[16][32];
  sm[rg][cp] = idx; sm[rg][cp + 1] = idy;
  __syncthreads();
  if (t < 32) {
    int best = -1;
#pragma unroll
    for (int g = 0; g < 16; g++) best = max(best, sm[g][t]);
    smolid[b * CW + t] = best;
  }
}

// ---------------- K0b: exact boundaries + W pack ----------------
__global__ __launch_bounds__(256) void k_bounds(
    const float* __restrict__ mat, const float* __restrict__ W,
    const int* __restrict__ smolid, int* __restrict__ strt,
    int4* __restrict__ wp) {
  int b = blockIdx.x, t = threadIdx.x;
  if (b < NGAP) {
    // gap between chunk b (last col p) and chunk b+1 (first col q)
    int p  = chunk_base(b) + CW - 1;
    int q  = chunk_base(b + 1);
    int ag = smolid[b * CW + CW - 1];   // molid(p)
    int bg = smolid[(b + 1) * CW];      // molid(q)
    if (bg == ag) return;
    int Wd = q - p;                     // columns p+1 .. q
    int nr = bg - ag;                   // rows ag+1 .. bg
    __shared__ int f1[512];
    int wave = t >> 6, l = t & 63;
    for (int rr = wave; rr < nr; rr += 4) {
      const float* rp = mat + (size_t)(ag + 1 + rr) * N_NODES + p + 1;
      int mn = 0x7fffffff;
      for (int i = l; i < Wd; i += 64)
        if (rp[i] != 0.f) { mn = i; break; }   // ascending -> first hit is min
#pragma unroll
      for (int o = 1; o < 64; o <<= 1) mn = min(mn, __shfl_xor(mn, o));
      if (l == 0) f1[rr] = mn;
    }
    __syncthreads();
    if (t == 0) {
      int run = 0x7fffffff;
      for (int rr = nr - 1; rr >= 0; rr--) {
        run = min(run, f1[rr]);
        strt[ag + 1 + rr] = p + 1 + run;
      }
    }
  } else if (b < NGAP + NCH) {
    // in-chunk transitions between adjacent sampled columns
    int cc = b - NGAP;
    if (t >= 1 && t < CW) {
      int prev = smolid[cc * CW + t - 1], cur = smolid[cc * CW + t];
      int col = chunk_base(cc) + t;
      for (int m = prev + 1; m <= cur; m++) strt[m] = col;
    }
  } else if (b == NGAP + NCH) {
    // cleanup: head (m <= molid(0)) -> 0 ; tail (m > molid(N-1)) -> N
    int first = smolid[0], last = smolid[NSAMP - 1];
    for (int m = t; m <= M_MOLS; m += 256) {
      if (m <= first) strt[m] = 0;
      else if (m > last) strt[m] = N_NODES;
    }
  } else {
    // W pack into MFMA B-fragment layout (bf16)
    int g  = (b - NGAP - NCH - 1) * 256 + t;   // 0..8191
    int l  = g & 63;
    int Ju = g >> 6;
    int J  = Ju >> 3, u = Ju & 7;
    int j  = J * 16 + (l & 15);
    int k0 = u * 32 + (l >> 4) * 8;
    short sv[8];
#pragma unroll
    for (int i = 0; i < 8; i++) sv[i] = f2bf(W[(size_t)(k0 + i) * ODIM + j]);
    wp[Ju * 64 + l] = *(int4*)sv;
  }
}

// ---------------- K2: fused — per molecule: 1 compute block + 2 writer blocks
__global__ __launch_bounds__(512, 4) void k_fused(
    const float* __restrict__ x, const float* __restrict__ wa,
    const float* __restrict__ ba, const int* __restrict__ strt,
    const int4* __restrict__ wp, const float* __restrict__ bias,
    float* __restrict__ out0, float* __restrict__ out1) {
  int b = blockIdx.x;
  int m = b / 3, role = b - m * 3;
  int t = threadIdx.x;
  int seg_s = strt[m], seg_e = strt[m + 1];

  if (role != 0) {
    // ---- writer: half a row of out1, zeros outside the weight window,
    // nontemporal so x stays cached for the pool re-read
    int s4 = seg_s >> 2, e4 = (seg_e + 3) >> 2;
    f32x4* orow = (f32x4*)out1 + (size_t)m * NF4;
    f32x4 z = {0.f, 0.f, 0.f, 0.f};
    int q0 = (role - 1) * HALF4;
    int q1 = q0 + HALF4;
    for (int q = q0 + t; q < q1; q += 512)
      if (q < s4 || q >= e4) __builtin_nontemporal_store(z, orow + q);
    return;
  }

  // ---- compute block: align -> softmax -> weight window -> MFMA pool
  int L = seg_e - seg_s;
  __shared__ float a_lds[A_CAP];
  __shared__ __align__(16) short xs[16 * 256];
  __shared__ float fred[8];

  // align: a[i] = x[seg_s+i,:].wa + ba  (8 threads per row, 64 rows/iter)
  float ba0 = ba[0];
  int sub = t & 7;
  float4 wv[8];
  {
    const float4* wr = (const float4*)wa + sub * 8;
#pragma unroll
    for (int i = 0; i < 8; i++) wv[i] = wr[i];
  }
  int nit = (L + 63) >> 6;
  for (int it = 0; it < nit; it++) {
    int ro  = it * 64 + (t >> 3);
    int row = seg_s + ro;
    float s = 0.f;
    if (row < seg_e) {
      const float4* xr = (const float4*)(x + (size_t)row * DIMK) + sub * 8;
#pragma unroll
      for (int i = 0; i < 8; i++) {
        float4 xv = xr[i];
        s += xv.x * wv[i].x + xv.y * wv[i].y + xv.z * wv[i].z + xv.w * wv[i].w;
      }
    }
    s += __shfl_xor(s, 1); s += __shfl_xor(s, 2); s += __shfl_xor(s, 4);
    if (sub == 0 && row < seg_e && ro < A_CAP) a_lds[ro] = s + ba0;
  }
  __syncthreads();

  // softmax over a_lds[0..L)
  float mx = -3e38f;
  for (int i = t; i < L; i += 512) mx = fmaxf(mx, a_lds[i]);
#pragma unroll
  for (int o = 1; o < 64; o <<= 1) mx = fmaxf(mx, __shfl_xor(mx, o));
  if ((t & 63) == 0) fred[t >> 6] = mx;
  __syncthreads();
  mx = fred[0];
#pragma unroll
  for (int i = 1; i < 8; i++) mx = fmaxf(mx, fred[i]);
  __syncthreads();
  float sm = 0.f;
  for (int i = t; i < L; i += 512) sm += __expf(a_lds[i] - mx);
#pragma unroll
  for (int o = 1; o < 64; o <<= 1) sm += __shfl_xor(sm, o);
  if ((t & 63) == 0) fred[t >> 6] = sm;
  __syncthreads();
  sm = 0.f;
#pragma unroll
  for (int i = 0; i < 8; i++) sm += fred[i];
  float inv = (sm > 0.f) ? 1.f / sm : 0.f;
  for (int i = t; i < L; i += 512) a_lds[i] = __expf(a_lds[i] - mx) * inv;
  __syncthreads();

  // weight window of out1 row (disjoint from writer blocks' range)
  {
    int s4 = seg_s >> 2, e4 = (seg_e + 3) >> 2;
    float4* orow = (float4*)out1 + (size_t)m * NF4;
    for (int q = s4 + t; q < e4; q += 512) {
      int n = q * 4;
      float4 o;
      o.x = (n     >= seg_s && n     < seg_e) ? a_lds[n     - seg_s] : 0.f;
      o.y = (n + 1 >= seg_s && n + 1 < seg_e) ? a_lds[n + 1 - seg_s] : 0.f;
      o.z = (n + 2 >= seg_s && n + 2 < seg_e) ? a_lds[n + 2 - seg_s] : 0.f;
      o.w = (n + 3 >= seg_s && n + 3 < seg_e) ? a_lds[n + 3 - seg_s] : 0.f;
      orow[q] = o;
    }
  }

  // fused h-GEMM + pool (x re-read is L2-hot: same rows as align pass)
  int wv_id = t >> 6, l = t & 63;
  bf16x8 wfrag[2][8];
#pragma unroll
  for (int t2 = 0; t2 < 2; t2++)
#pragma unroll
    for (int u = 0; u < 8; u++)
      wfrag[t2][u] = __builtin_bit_cast(bf16x8, wp[((wv_id * 2 + t2) * 8 + u) * 64 + l]);
  float bias_r[2];
#pragma unroll
  for (int t2 = 0; t2 < 2; t2++) bias_r[t2] = bias[wv_id * 32 + t2 * 16 + (l & 15)];

  float pooled[2] = {0.f, 0.f};
  int r = l & 15, g = l >> 4;
  int swr = (r & 7) << 4;

  int srow = t >> 5;            // staging: 16 rows, 32 threads each
  int c0b  = (t & 31) * 16;     // byte col offset within row
  int ssw  = (srow & 7) << 4;
  char* lb = (char*)xs;

  int nt2 = (L + 15) >> 4;
  for (int tile = 0; tile < nt2; tile++) {
    int base = seg_s + tile * 16;
    __syncthreads();
    {
      int n = base + srow;
      short sv[8];
      if (n < seg_e) {
        const float4* src = (const float4*)(x + (size_t)n * DIMK) + (t & 31) * 2;
        float4 A = src[0], B = src[1];
        sv[0] = f2bf(A.x); sv[1] = f2bf(A.y); sv[2] = f2bf(A.z); sv[3] = f2bf(A.w);
        sv[4] = f2bf(B.x); sv[5] = f2bf(B.y); sv[6] = f2bf(B.z); sv[7] = f2bf(B.w);
      } else {
#pragma unroll
        for (int i = 0; i < 8; i++) sv[i] = 0;
      }
      *(int4*)(lb + (srow << 9) + (c0b ^ ssw)) = *(int4*)sv;
    }
    __syncthreads();
    bf16x8 af[8];
#pragma unroll
    for (int u = 0; u < 8; u++)
      af[u] = __builtin_bit_cast(bf16x8,
                *(const int4*)(lb + (r << 9) + (((u << 6) + (g << 4)) ^ swr)));
#pragma unroll
    for (int t2 = 0; t2 < 2; t2++) {
      f32x4 acc = {0.f, 0.f, 0.f, 0.f};
#pragma unroll
      for (int u = 0; u < 8; u++)
        acc = __builtin_amdgcn_mfma_f32_16x16x32_bf16(af[u], wfrag[t2][u], acc, 0, 0, 0);
      float p = 0.f;
#pragma unroll
      for (int i = 0; i < 4; i++) {
        int ridx = tile * 16 + (g << 2) + i;
        float wgt = (ridx < L) ? a_lds[ridx] : 0.f;
        float h = acc[i] + bias_r[t2];
        h = h > 0.f ? h : 0.01f * h;
        p += wgt * h;
      }
      pooled[t2] += p;
    }
  }
#pragma unroll
  for (int t2 = 0; t2 < 2; t2++) {
    float p = pooled[t2];
    p += __shfl_xor(p, 16);
    p += __shfl_xor(p, 32);
    pooled[t2] = p;
  }
  if (l < 16) {
#pragma unroll
    for (int t2 = 0; t2 < 2; t2++)
      out0[m * ODIM + wv_id * 32 + t2 * 16 + l] = pooled[t2];
  }
}

extern "C" void kernel_launch(void* const* d_in, const int* in_sizes, int n_in,
                              void* d_out, int out_size, void* d_ws, size_t ws_size,
                              hipStream_t stream) {
  const float* x   = (const float*)d_in[0];
  const float* mat = (const float*)d_in[1];
  // d_in[2] (mol_node_mask) redundant with mol_node_matrix — never read
  const float* W   = (const float*)d_in[3];
  const float* bA  = (const float*)d_in[4];
  const float* wa  = (const float*)d_in[5];
  const float* ba  = (const float*)d_in[6];

  float* out0 = (float*)d_out;
  float* out1 = out0 + (size_t)M_MOLS * ODIM;

  char* ws     = (char*)d_ws;
  int*  smolid = (int*) (ws);            // 3168 ints
  int*  strt   = (int*) (ws + 16384);    // 513 ints
  int4* wp     = (int4*)(ws + 20480);    // 128 KiB

  k_samp  <<<NCH, 256, 0, stream>>>(mat, smolid);
  k_bounds<<<B2_GRID, 256, 0, stream>>>(mat, W, smolid, strt, wp);
  k_fused <<<M_MOLS * 3, 512, 0, stream>>>(x, wa, ba, strt, wp, bA, out0, out1);
}

// Round 7
// 52.920 us; speedup vs baseline: 1.4966x; 1.0732x over previous
//
#include <hip/hip_runtime.h>
#include <cstdint>
#include <cstddef>

#define N_NODES 50000
#define M_MOLS  512
#define DIMK    256
#define ODIM    256

// sampled-boundary parameters
#define NCH   99
#define CW    32
#define NSAMP (NCH * CW)      // 3168 sampled columns, monotone molid
#define NGAP  (NCH - 1)       // 98 inter-chunk gaps

#define NB_WPACK 32
#define K0_GRID  (NCH + NB_WPACK)              // 131

#define NB_ALIGN 1563         // 50000 rows * 8 threads / 256
#define K1_GRID  (NGAP + NCH + 1 + NB_ALIGN)   // 1761

#define POOL_BLOCKS 512
#define WPB   4               // writer blocks per out1 row
#define QPB   3125            // float4 per writer block (4*3125 = 12500 = row)
#define NB_WRITE (M_MOLS * WPB)                // 2048
#define K2_GRID  (POOL_BLOCKS + NB_WRITE)      // 2560
#define NF4   (N_NODES / 4)   // 12500 float4 per out1 row
#define A_CAP 1024

typedef float  f32x4  __attribute__((ext_vector_type(4)));
typedef __bf16 bf16x8 __attribute__((ext_vector_type(8)));

static __device__ __forceinline__ short f2bf(float f) {
  unsigned u = __builtin_bit_cast(unsigned, f);
  u = u + 0x7fffu + ((u >> 16) & 1u);   // RNE to bf16
  return (short)(u >> 16);
}

static __device__ __forceinline__ int chunk_base(int c) {
  return (c < NCH - 1) ? c * 512 : (N_NODES - CW);   // 49968 for last
}

// ---------------- K0: sampled molid + W pack ----------------
__global__ __launch_bounds__(256) void k_prep(
    const float* __restrict__ mat, const float* __restrict__ W,
    int* __restrict__ smolid, int4* __restrict__ wp) {
  int b = blockIdx.x, t = threadIdx.x;
  if (b < NCH) {
    int base = chunk_base(b);
    int cp = (t & 15) * 2;      // column pair
    int rg = t >> 4;            // 16 row-groups of 32 rows
    int idx = -1, idy = -1;
    const float* p0 = mat + (size_t)(rg * 32) * N_NODES + base + cp;
#pragma unroll 16
    for (int r = 0; r < 32; r++) {
      float2 v = *(const float2*)(p0 + (size_t)r * N_NODES);
      if (v.x != 0.f) idx = rg * 32 + r;
      if (v.y != 0.f) idy = rg * 32 + r;
    }
    __shared__ int sm[16][32];
    sm[rg][cp] = idx; sm[rg][cp + 1] = idy;
    __syncthreads();
    if (t < 32) {
      int best = -1;
#pragma unroll
      for (int g = 0; g < 16; g++) best = max(best, sm[g][t]);
      smolid[b * CW + t] = best;
    }
  } else {
    // W pack into MFMA B-fragment layout (bf16)
    int g  = (b - NCH) * 256 + t;   // 0..8191
    int l  = g & 63;
    int Ju = g >> 6;
    int J  = Ju >> 3, u = Ju & 7;
    int j  = J * 16 + (l & 15);
    int k0 = u * 32 + (l >> 4) * 8;
    short sv[8];
#pragma unroll
    for (int i = 0; i < 8; i++) sv[i] = f2bf(W[(size_t)(k0 + i) * ODIM + j]);
    wp[Ju * 64 + l] = *(int4*)sv;
  }
}

// ---------------- K1: exact boundaries + align GEMV (pure read) ----------------
__global__ __launch_bounds__(256) void k_bal(
    const float* __restrict__ x, const float* __restrict__ mat,
    const float* __restrict__ wa, const float* __restrict__ ba,
    const int* __restrict__ smolid, int* __restrict__ strt,
    float* __restrict__ a) {
  int b = blockIdx.x, t = threadIdx.x;
  if (b < NGAP) {
    // gap between chunk b (last col p) and chunk b+1 (first col q)
    int p  = chunk_base(b) + CW - 1;
    int q  = chunk_base(b + 1);
    int ag = smolid[b * CW + CW - 1];   // molid(p)
    int bg = smolid[(b + 1) * CW];      // molid(q)
    if (bg == ag) return;
    int Wd = q - p;                     // columns p+1 .. q
    int nr = bg - ag;                   // rows ag+1 .. bg
    __shared__ int f1[512];
    int wave = t >> 6, l = t & 63;
    for (int rr = wave; rr < nr; rr += 4) {
      const float* rp = mat + (size_t)(ag + 1 + rr) * N_NODES + p + 1;
      int mn = 0x7fffffff;
      for (int i = l; i < Wd; i += 64)
        if (rp[i] != 0.f) { mn = i; break; }   // ascending -> first hit is min
#pragma unroll
      for (int o = 1; o < 64; o <<= 1) mn = min(mn, __shfl_xor(mn, o));
      if (l == 0) f1[rr] = mn;
    }
    __syncthreads();
    if (t == 0) {
      int run = 0x7fffffff;
      for (int rr = nr - 1; rr >= 0; rr--) {
        run = min(run, f1[rr]);
        strt[ag + 1 + rr] = p + 1 + run;
      }
    }
  } else if (b < NGAP + NCH) {
    // in-chunk transitions between adjacent sampled columns
    int cc = b - NGAP;
    if (t >= 1 && t < CW) {
      int prev = smolid[cc * CW + t - 1], cur = smolid[cc * CW + t];
      int col = chunk_base(cc) + t;
      for (int m = prev + 1; m <= cur; m++) strt[m] = col;
    }
  } else if (b == NGAP + NCH) {
    // cleanup: head (m <= molid(0)) -> 0 ; tail (m > molid(N-1)) -> N
    int first = smolid[0], last = smolid[NSAMP - 1];
    for (int m = t; m <= M_MOLS; m += 256) {
      if (m <= first) strt[m] = 0;
      else if (m > last) strt[m] = N_NODES;
    }
  } else {
    // align: a[n] = x[n,:].w_align + b_align, 8 threads per row
    int tid = (b - NGAP - NCH - 1) * 256 + t;
    int row = tid >> 3, sub = tid & 7;
    if (row >= N_NODES) return;
    const float4* xr = (const float4*)(x + (size_t)row * DIMK) + sub * 8;
    const float4* wr = (const float4*)wa + sub * 8;
    float s = 0.f;
#pragma unroll
    for (int i = 0; i < 8; i++) {
      float4 xv = xr[i], wv = wr[i];
      s += xv.x * wv.x + xv.y * wv.y + xv.z * wv.z + xv.w * wv.w;
    }
    s += __shfl_xor(s, 1); s += __shfl_xor(s, 2); s += __shfl_xor(s, 4);
    if (sub == 0) a[row] = s + ba[0];
  }
}

// ---------------- K2: pool blocks (first) + dedicated zero writers ----------
// Pool block m: softmax(a[seg]) -> window write of out1 row m -> MFMA pool.
// Writer blocks: zeros of out1, skipping window float4s (disjoint addresses).
__global__ __launch_bounds__(256, 2) void k_out(
    const float* __restrict__ x, const float* __restrict__ a,
    const int* __restrict__ strt, const int4* __restrict__ wp,
    const float* __restrict__ bias, float* __restrict__ out0,
    float* __restrict__ out1) {
  int b = blockIdx.x;
  int t = threadIdx.x;

  if (b >= POOL_BLOCKS) {
    // ---- writer: quarter of a row, contiguous, regular stores
    int wb = b - POOL_BLOCKS;            // 0..2047
    int m = wb >> 2, quarter = wb & 3;
    int s = strt[m], e = strt[m + 1];
    int s4 = s >> 2, e4 = (e + 3) >> 2;
    float4* orow = (float4*)out1 + (size_t)m * NF4;
    int q0 = quarter * QPB, q1 = q0 + QPB;
    float4 z; z.x = z.y = z.z = z.w = 0.f;
    for (int q = q0 + t; q < q1; q += 256)
      if (q < s4 || q >= e4) orow[q] = z;
    return;
  }

  // ---- pool block for molecule m = b
  int m = b;
  int seg_s = strt[m], seg_e = strt[m + 1];
  int L = seg_e - seg_s;

  __shared__ float a_lds[A_CAP];
  __shared__ __align__(16) short xs[16 * 256];
  __shared__ float fred[4];

  // softmax over a[seg] in LDS
  for (int i = t; i < L; i += 256) a_lds[i] = a[seg_s + i];
  __syncthreads();
  float mx = -3e38f;
  for (int i = t; i < L; i += 256) mx = fmaxf(mx, a_lds[i]);
#pragma unroll
  for (int o = 1; o < 64; o <<= 1) mx = fmaxf(mx, __shfl_xor(mx, o));
  if ((t & 63) == 0) fred[t >> 6] = mx;
  __syncthreads();
  mx = fmaxf(fmaxf(fred[0], fred[1]), fmaxf(fred[2], fred[3]));
  __syncthreads();
  float sm = 0.f;
  for (int i = t; i < L; i += 256) sm += __expf(a_lds[i] - mx);
#pragma unroll
  for (int o = 1; o < 64; o <<= 1) sm += __shfl_xor(sm, o);
  if ((t & 63) == 0) fred[t >> 6] = sm;
  __syncthreads();
  sm = fred[0] + fred[1] + fred[2] + fred[3];
  float inv = (sm > 0.f) ? 1.f / sm : 0.f;
  for (int i = t; i < L; i += 256) a_lds[i] = __expf(a_lds[i] - mx) * inv;
  __syncthreads();

  // window write (exactly the float4s the writers skip)
  {
    int s4 = seg_s >> 2, e4 = (seg_e + 3) >> 2;
    float4* orow = (float4*)out1 + (size_t)m * NF4;
    for (int q = s4 + t; q < e4; q += 256) {
      int n = q * 4;
      float4 o;
      o.x = (n     >= seg_s && n     < seg_e) ? a_lds[n     - seg_s] : 0.f;
      o.y = (n + 1 >= seg_s && n + 1 < seg_e) ? a_lds[n + 1 - seg_s] : 0.f;
      o.z = (n + 2 >= seg_s && n + 2 < seg_e) ? a_lds[n + 2 - seg_s] : 0.f;
      o.w = (n + 3 >= seg_s && n + 3 < seg_e) ? a_lds[n + 3 - seg_s] : 0.f;
      orow[q] = o;
    }
  }

  // fused h-GEMM + pool (x is LLC-hot after K1's align pass)
  int wave = t >> 6, l = t & 63;
  bf16x8 wfrag[4][8];
#pragma unroll
  for (int t2 = 0; t2 < 4; t2++)
#pragma unroll
    for (int u = 0; u < 8; u++)
      wfrag[t2][u] = __builtin_bit_cast(bf16x8, wp[((wave * 4 + t2) * 8 + u) * 64 + l]);
  float bias_r[4];
#pragma unroll
  for (int t2 = 0; t2 < 4; t2++) bias_r[t2] = bias[wave * 64 + t2 * 16 + (l & 15)];

  float pooled[4] = {0.f, 0.f, 0.f, 0.f};
  int r = l & 15, g = l >> 4;
  int swr = (r & 7) << 4;
  char* lb = (char*)xs;

  int nt2 = (L + 15) >> 4;
  for (int tile = 0; tile < nt2; tile++) {
    int base = seg_s + tile * 16;
    __syncthreads();
    {
      int row = t >> 4;
      int c0  = (t & 15) * 16;
      int n   = base + row;
      short sv[16];
      if (n < seg_e) {
        const float4* src = (const float4*)(x + (size_t)n * DIMK + c0);
        float4 A = src[0], B = src[1], C = src[2], D = src[3];
        sv[0]  = f2bf(A.x); sv[1]  = f2bf(A.y); sv[2]  = f2bf(A.z); sv[3]  = f2bf(A.w);
        sv[4]  = f2bf(B.x); sv[5]  = f2bf(B.y); sv[6]  = f2bf(B.z); sv[7]  = f2bf(B.w);
        sv[8]  = f2bf(C.x); sv[9]  = f2bf(C.y); sv[10] = f2bf(C.z); sv[11] = f2bf(C.w);
        sv[12] = f2bf(D.x); sv[13] = f2bf(D.y); sv[14] = f2bf(D.z); sv[15] = f2bf(D.w);
      } else {
#pragma unroll
        for (int i = 0; i < 16; i++) sv[i] = 0;
      }
      int sw = (row & 7) << 4;
      *(int4*)(lb + (row << 9) + (((c0 << 1)     ) ^ sw)) = *(int4*)(sv);
      *(int4*)(lb + (row << 9) + (((c0 << 1) + 16) ^ sw)) = *(int4*)(sv + 8);
    }
    __syncthreads();
    bf16x8 af[8];
#pragma unroll
    for (int u = 0; u < 8; u++)
      af[u] = __builtin_bit_cast(bf16x8,
                *(const int4*)(lb + (r << 9) + (((u << 6) + (g << 4)) ^ swr)));
#pragma unroll
    for (int t2 = 0; t2 < 4; t2++) {
      f32x4 acc = {0.f, 0.f, 0.f, 0.f};
#pragma unroll
      for (int u = 0; u < 8; u++)
        acc = __builtin_amdgcn_mfma_f32_16x16x32_bf16(af[u], wfrag[t2][u], acc, 0, 0, 0);
      float p = 0.f;
#pragma unroll
      for (int i = 0; i < 4; i++) {
        int ridx = tile * 16 + (g << 2) + i;
        float wgt = (ridx < L) ? a_lds[ridx] : 0.f;
        float h = acc[i] + bias_r[t2];
        h = h > 0.f ? h : 0.01f * h;
        p += wgt * h;
      }
      pooled[t2] += p;
    }
  }
#pragma unroll
  for (int t2 = 0; t2 < 4; t2++) {
    float p = pooled[t2];
    p += __shfl_xor(p, 16);
    p += __shfl_xor(p, 32);
    pooled[t2] = p;
  }
  if (l < 16) {
#pragma unroll
    for (int t2 = 0; t2 < 4; t2++)
      out0[m * ODIM + wave * 64 + t2 * 16 + l] = pooled[t2];
  }
}

extern "C" void kernel_launch(void* const* d_in, const int* in_sizes, int n_in,
                              void* d_out, int out_size, void* d_ws, size_t ws_size,
                              hipStream_t stream) {
  const float* x   = (const float*)d_in[0];
  const float* mat = (const float*)d_in[1];
  // d_in[2] (mol_node_mask) redundant with mol_node_matrix — never read
  const float* W   = (const float*)d_in[3];
  const float* bA  = (const float*)d_in[4];
  const float* wa  = (const float*)d_in[5];
  const float* ba  = (const float*)d_in[6];

  float* out0 = (float*)d_out;
  float* out1 = out0 + (size_t)M_MOLS * ODIM;

  char*  ws     = (char*)d_ws;
  float* a      = (float*)(ws);              // 50000 f
  int*   smolid = (int*)  (ws + 200064);     // 3168 i
  int*   strt   = (int*)  (ws + 212800);     // 513 i
  int4*  wp     = (int4*) (ws + 215040);     // 128 KiB

  k_prep<<<K0_GRID, 256, 0, stream>>>(mat, W, smolid, wp);
  k_bal <<<K1_GRID, 256, 0, stream>>>(x, mat, wa, ba, smolid, strt, a);
  k_out <<<K2_GRID, 256, 0, stream>>>(x, a, strt, wp, bA, out0, out1);
}